// Round 12
// baseline (356.492 us; speedup 1.0000x reference)
//
#include <hip/hip_runtime.h>
#include <cmath>

namespace {

typedef __bf16 bf16x8 __attribute__((ext_vector_type(8)));
typedef float f32x4 __attribute__((ext_vector_type(4)));
typedef unsigned short u16x8 __attribute__((ext_vector_type(8)));

enum : int { N = 128, T = 32, D = 512, H = 1024, V = 16384, R = N * T, NP = V / 64 };

// ---- workspace layout (float units) ----
enum : size_t {
  OFF_XB    = 0,                                // 4096x512 bf16
  OFF_FEATB = OFF_XB + 1048576,                 // 128x512 bf16
  OFF_H0B   = OFF_FEATB + 32768,                // 128x1024 bf16
  OFF_HALLB = OFF_H0B + 65536,                  // 4096x1024 bf16
  OFF_WPT   = OFF_HALLB + 2097152,              // 1024x512 bf16
  OFF_WXT   = OFF_WPT + 262144,                 // 1024x512 bf16
  OFF_WHT   = OFF_WXT + 262144,                 // 1024x1024 bf16
  OFF_WVT   = OFF_WHT + 524288,                 // 16384x1024 bf16
  OFF_XW    = OFF_WVT + 8388608,                // 4096x1024 f32
  OFF_PSUM  = OFF_XW + 4194304,                 // 4096x256 f32
  OFF_BLK   = OFF_PSUM + 1048576,               // 1024
  OFF_BAR   = OFF_BLK + 1024,                   // 4224 ints: 8 ctrs + 256 flags, 64B apart
};

__device__ inline unsigned short f2b(float x) {
  union { float f; unsigned u; } v; v.f = x;
  unsigned r = v.u + 0x7fffu + ((v.u >> 16) & 1u);
  return (unsigned short)(r >> 16);
}
__device__ inline float b2f(unsigned short b) {
  union { unsigned u; float f; } v; v.u = ((unsigned)b) << 16; return v.f;
}

#define GLOAD_LDS16(gptr, lptr)                                            \
  __builtin_amdgcn_global_load_lds(                                        \
      (const __attribute__((address_space(1))) unsigned int*)(gptr),       \
      (__attribute__((address_space(3))) unsigned int*)(lptr), 16, 0, 0)

#define VMCNT(n) asm volatile("s_waitcnt vmcnt(" #n ")" ::: "memory")
#define SBAR()   asm volatile("s_barrier" ::: "memory")

__device__ inline int get_xcd() {
  int x;
  asm volatile("s_getreg_b32 %0, hwreg(HW_REG_XCC_ID)" : "=s"(x));
  return x & 7;
}

// ---------- all weight transposes fused: dst[n][k] = bf16(src[k][n]) ----------
__global__ __launch_bounds__(256) void k_cvt_t_all(
    const float* __restrict__ Wv, const float* __restrict__ Wh,
    const float* __restrict__ Wp, const float* __restrict__ Wx,
    unsigned short* __restrict__ WvT, unsigned short* __restrict__ WhT,
    unsigned short* __restrict__ WpT, unsigned short* __restrict__ WxT) {
  __shared__ float tile[64][65];
  const float* src; unsigned short* dst; int Ks, Ns, bx, by;
  int b = blockIdx.x;
  if (b < 4096)      { src = Wv; dst = WvT; Ks = H; Ns = V; bx = b & 255; by = b >> 8; }
  else if (b < 4352) { int l = b - 4096; src = Wh; dst = WhT; Ks = H; Ns = H; bx = l & 15; by = l >> 4; }
  else if (b < 4480) { int l = b - 4352; src = Wp; dst = WpT; Ks = D; Ns = H; bx = l & 15; by = l >> 4; }
  else               { int l = b - 4480; src = Wx; dst = WxT; Ks = D; Ns = H; bx = l & 15; by = l >> 4; }
  const int n0 = bx * 64, k0 = by * 64;
  const int tr = threadIdx.x >> 4;
  const int tc4 = (threadIdx.x & 15) * 4;
#pragma unroll
  for (int i = 0; i < 4; ++i) {
    float4 v = *reinterpret_cast<const float4*>(
        &src[(size_t)(k0 + tr + i * 16) * Ns + n0 + tc4]);
    tile[tr + i * 16][tc4 + 0] = v.x;
    tile[tr + i * 16][tc4 + 1] = v.y;
    tile[tr + i * 16][tc4 + 2] = v.z;
    tile[tr + i * 16][tc4 + 3] = v.w;
  }
  __syncthreads();
  const int nr = threadIdx.x >> 3;
  const int k8 = (threadIdx.x & 7) * 8;
#pragma unroll
  for (int i = 0; i < 2; ++i) {
    int n = nr + i * 32;
    u16x8 o;
#pragma unroll
    for (int j = 0; j < 8; ++j) o[j] = f2b(tile[k8 + j][n]);
    *reinterpret_cast<u16x8*>(&dst[(size_t)(n0 + n) * Ks + k0 + k8]) = o;
  }
}

// ---------- fused: embedding gather+cvt | feat cvt ----------
__global__ __launch_bounds__(256) void k_inputs(const int* __restrict__ cap,
                                                const float* __restrict__ Wemb,
                                                const float* __restrict__ feat,
                                                unsigned short* __restrict__ XB,
                                                unsigned short* __restrict__ featB) {
  if (blockIdx.x < 4096) {
    int idx = blockIdx.x * 256 + threadIdx.x;
    int r = idx >> 8;
    int w2 = (idx & 255) * 2;
    int n = r >> 5, t = r & 31;
    const float* srow = Wemb + (size_t)cap[n * 33 + t] * D;
    float2 v = *reinterpret_cast<const float2*>(srow + w2);
    ushort2 o; o.x = f2b(v.x); o.y = f2b(v.y);
    *reinterpret_cast<ushort2*>(XB + (size_t)r * D + w2) = o;
  } else {
    int i = ((blockIdx.x - 4096) * 256 + threadIdx.x) * 2;
    float2 v = *reinterpret_cast<const float2*>(feat + i);
    ushort2 o; o.x = f2b(v.x); o.y = f2b(v.y);
    *reinterpret_cast<ushort2*>(featB + i) = o;
  }
}

// ---------- small bf16 MFMA GEMM (h0, xW): 2-phase structure ----------
template <int BM, int BN, int WM, int WN, int EPI>
__global__ __launch_bounds__(256) void gemm_bt(
    const unsigned short* __restrict__ A, int lda,
    const unsigned short* __restrict__ B, int K,
    void* __restrict__ C, int ldc,
    const float* __restrict__ bias) {
  constexpr int BK = 64;
  constexpr int WAVES_N = BN / WN;
  constexpr int NW = (BM / WM) * (BN / WN);
  constexpr int FM = WM / 16, FN = WN / 16;
  __shared__ __align__(16) unsigned short As[BM * BK];
  __shared__ __align__(16) unsigned short Bs[BN * BK];
  int tid = threadIdx.x, lane = tid & 63, wave = tid >> 6;
  int wr = wave / WAVES_N, wc = wave % WAVES_N;
  int row0 = blockIdx.y * BM, col0 = blockIdx.x * BN;

  f32x4 acc[FM][FN] = {};
  const unsigned short* Ab = A + (size_t)row0 * lda;
  const unsigned short* Bb = B + (size_t)col0 * K;
  int srow = lane >> 3;
  int skof = (((lane & 7) ^ (lane >> 3))) * 8;

  for (int k0 = 0; k0 < K; k0 += BK) {
    __syncthreads();
#pragma unroll
    for (int c = wave; c < BM / 8; c += NW)
      GLOAD_LDS16(Ab + (size_t)(c * 8 + srow) * lda + k0 + skof, As + c * 512);
#pragma unroll
    for (int c = wave; c < BN / 8; c += NW)
      GLOAD_LDS16(Bb + (size_t)(c * 8 + srow) * K + k0 + skof, Bs + c * 512);
    asm volatile("s_waitcnt vmcnt(0)" ::: "memory");
    __syncthreads();
#pragma unroll
    for (int kk = 0; kk < 2; ++kk) {
      int g = ((kk * 4 + (lane >> 4)) ^ (lane & 7)) * 8;
      bf16x8 af[FM], bfr[FN];
#pragma unroll
      for (int m = 0; m < FM; ++m)
        af[m] = *reinterpret_cast<const bf16x8*>(
            &As[(wr * WM + m * 16 + (lane & 15)) * BK + g]);
#pragma unroll
      for (int n = 0; n < FN; ++n)
        bfr[n] = *reinterpret_cast<const bf16x8*>(
            &Bs[(wc * WN + n * 16 + (lane & 15)) * BK + g]);
#pragma unroll
      for (int m = 0; m < FM; ++m)
#pragma unroll
        for (int n = 0; n < FN; ++n)
          acc[m][n] = __builtin_amdgcn_mfma_f32_16x16x32_bf16(af[m], bfr[n], acc[m][n], 0, 0, 0);
    }
  }

  int lr4 = (lane >> 4) * 4, lc = lane & 15;
#pragma unroll
  for (int m = 0; m < FM; ++m)
#pragma unroll
    for (int n = 0; n < FN; ++n) {
      int cg = col0 + wc * WN + n * 16 + lc;
      float bcol = bias[cg];
#pragma unroll
      for (int j = 0; j < 4; ++j) {
        int r = row0 + wr * WM + m * 16 + lr4 + j;
        float v = acc[m][n][j] + bcol;
        if constexpr (EPI == 0) ((float*)C)[(size_t)r * ldc + cg] = v;
        else ((unsigned short*)C)[(size_t)r * ldc + cg] = f2b(v);
      }
    }
}

// ---------- 8-phase 256x256 scores GEMM + fused fixed-max LSE partials ----------
// Row-major LDS [row][64] + granule-XOR swizzle (R11-proven conflict-free).
// Counted vmcnt(4) (never 0 mid-loop), raw s_barrier (no implicit drain),
// setprio around MFMA clusters. 512 thr = 8 waves (2M x 4N), acc 128x64/wave.
__global__ __launch_bounds__(512, 1) void k_scores8(
    const unsigned short* __restrict__ A,   // HALLB [R][1024]
    const unsigned short* __restrict__ B,   // WvT [V][1024]
    const float* __restrict__ bias,
    float* __restrict__ psum) {
  constexpr int K = 1024, BK = 64, NT = K / BK;
  __shared__ __align__(16) unsigned short As[2][256 * BK];
  __shared__ __align__(16) unsigned short Bs[2][256 * BK];
  const int tid = threadIdx.x, lane = tid & 63, wave = tid >> 6;
  const int wr = wave >> 2, wc = wave & 3;
  const int lo = lane & 15, hi = lane >> 4;
  // XCD-aware 1-D decode: xcd = o&7 owns an 8-wide col strip x 16 rows
  const int o = blockIdx.x;
  const int bx = (o & 7) * 8 + ((o >> 3) & 7);
  const int by = o >> 6;
  const int row0 = by * 256, col0 = bx * 256;
  const unsigned short* Ab = A + (size_t)row0 * K;
  const unsigned short* Bb = B + (size_t)col0 * K;
  const int srow = lane >> 3;
  const int skof = ((lane & 7) ^ (lane >> 3)) * 8;

  f32x4 acc[8][4] = {};

  // stage unit u of tile t: A rows [u*64,u*64+64) + B rows same; 2 loads/thread
#define STAGE_U(buf, u, t)                                                      \
  do {                                                                          \
    GLOAD_LDS16(Ab + (size_t)((u) * 64 + wave * 8 + srow) * K + (t) * BK + skof, \
                As[buf] + ((u) * 8 + wave) * 512);                              \
    GLOAD_LDS16(Bb + (size_t)((u) * 64 + wave * 8 + srow) * K + (t) * BK + skof, \
                Bs[buf] + ((u) * 8 + wave) * 512);                              \
  } while (0)

  // prologue: tile 0 fully staged (8 loads/thread outstanding)
  STAGE_U(0, 0, 0); STAGE_U(0, 1, 0); STAGE_U(0, 2, 0); STAGE_U(0, 3, 0);

  for (int t = 0; t < NT; ++t) {
    const int cur = t & 1, nxt = cur ^ 1;
    const unsigned short* a = As[cur];
    const unsigned short* b = Bs[cur];
#pragma unroll
    for (int p = 0; p < 4; ++p) {
      const int kk = p >> 1, mh = p & 1;
      if (p == 0) {
        // issue first half of tile t+1, then wait ONLY for tile t (counted)
        if (t + 1 < NT) {
          STAGE_U(nxt, 0, t + 1);
          STAGE_U(nxt, 1, t + 1);
          VMCNT(4);             // 12 outstanding -> oldest 8 (tile t) landed
        } else {
          VMCNT(0);             // epilogue drain
        }
        SBAR();                 // tile t visible to all waves
      } else if (p == 1) {
        if (t + 1 < NT) STAGE_U(nxt, 2, t + 1);
      } else if (p == 2) {
        if (t + 1 < NT) STAGE_U(nxt, 3, t + 1);
      }
      const int g = ((kk * 4 + hi) ^ (lo & 7)) * 8;
      bf16x8 af[4], bfr[4];
#pragma unroll
      for (int m = 0; m < 4; ++m)
        af[m] = *reinterpret_cast<const bf16x8*>(
            &a[(wr * 128 + (mh * 4 + m) * 16 + lo) * BK + g]);
#pragma unroll
      for (int n = 0; n < 4; ++n)
        bfr[n] = *reinterpret_cast<const bf16x8*>(
            &b[(wc * 64 + n * 16 + lo) * BK + g]);
      __builtin_amdgcn_s_setprio(1);
#pragma unroll
      for (int m = 0; m < 4; ++m)
#pragma unroll
        for (int n = 0; n < 4; ++n)
          acc[mh * 4 + m][n] = __builtin_amdgcn_mfma_f32_16x16x32_bf16(
              af[m], bfr[n], acc[mh * 4 + m][n], 0, 0, 0);
      __builtin_amdgcn_s_setprio(0);
      SBAR();                   // phase align; phase-3 bar guards buffer reuse
    }
  }
#undef STAGE_U

  // epilogue: fixed-max LSE partials at 64-col granularity
  float bb[4];
#pragma unroll
  for (int n = 0; n < 4; ++n) bb[n] = bias[col0 + wc * 64 + n * 16 + lo] - 8.0f;
  const int p_idx = (col0 + wc * 64) >> 6;
#pragma unroll
  for (int m = 0; m < 8; ++m) {
#pragma unroll
    for (int j = 0; j < 4; ++j) {
      int r = row0 + wr * 128 + m * 16 + hi * 4 + j;
      float se = 0.f;
#pragma unroll
      for (int n = 0; n < 4; ++n) se += expf(acc[m][n][j] + bb[n]);
#pragma unroll
      for (int off = 8; off >= 1; off >>= 1) se += __shfl_xor(se, off);
      if (lo == 0) psum[(size_t)r * NP + p_idx] = se;
    }
  }
}

// ---------- persistent RNN v6: XCD-LOCAL recurrences, atomic flags [R10 proven] ----------
__global__ __launch_bounds__(256, 1) void k_rnn_persist(
    const unsigned short* __restrict__ h0B,
    const unsigned short* __restrict__ WhT,   // [outcol][k] bf16
    const float* __restrict__ xW,             // [R][H] f32
    unsigned short* __restrict__ HALLB,       // [R][H] bf16
    int* __restrict__ bar) {                  // [0..127]: 8 ctrs; [128..]: 256 flags
  __shared__ __align__(16) unsigned short WhS[32 * 1024];
  __shared__ __align__(16) unsigned short AS[16 * 1024];
  __shared__ float red[2][64][4];
  __shared__ int slotS;
  const int tid = threadIdx.x, lane = tid & 63, wave = tid >> 6;
  const int kh = wave >> 1, ch = wave & 1;
  const int hi = lane >> 4, lo = lane & 15;

  const int xcd = get_xcd();
  if (tid == 0)
    slotS = __hip_atomic_fetch_add(&bar[xcd * 16], 1, __ATOMIC_RELAXED,
                                   __HIP_MEMORY_SCOPE_AGENT);
  __syncthreads();
  const int slot = slotS;
  if (slot >= 32) return;

  const int n0 = xcd * 16;
  const int c0 = slot * 32;
  int* const myflag = &bar[128 + (xcd * 32 + slot) * 16];
  int* const grpflags = &bar[128 + (xcd * 32) * 16];

  for (int c = wave; c < 64; c += 4) {
    int row = c >> 1, half = c & 1;
    int sg = (half * 64 + lane) ^ (row & 7);
    GLOAD_LDS16(WhT + (size_t)(c0 + row) * 1024 + sg * 8,
                WhS + row * 1024 + half * 512);
  }

  const unsigned short* ar = AS + (size_t)lo * 1024;
  const unsigned short* br = WhS + (size_t)(ch * 16 + lo) * 1024;
  const int col = c0 + ch * 16 + lo;

  for (int t = 0; t < T; ++t) {
    const unsigned short* Aptr =
        (t == 0) ? h0B + (size_t)n0 * H : HALLB + ((size_t)n0 * T + (t - 1)) * H;
    const size_t astr = (t == 0) ? (size_t)H : (size_t)T * H;
    for (int c = wave; c < 32; c += 4) {
      int row = c >> 1, half = c & 1;
      int sg = (half * 64 + lane) ^ (row & 7);
      GLOAD_LDS16(Aptr + (size_t)row * astr + sg * 8,
                  AS + row * 1024 + half * 512);
    }
    float xw[4] = {0.f, 0.f, 0.f, 0.f};
    if (kh == 0) {
#pragma unroll
      for (int j = 0; j < 4; ++j)
        xw[j] = xW[((size_t)(n0 + hi * 4 + j) * T + t) * H + col];
    }
    asm volatile("s_waitcnt vmcnt(0)" ::: "memory");
    __syncthreads();

    f32x4 acc = {0.f, 0.f, 0.f, 0.f};
#pragma unroll
    for (int kk2 = 0; kk2 < 16; ++kk2) {
      int kk = kh * 16 + kk2;
      int g = ((kk * 4 + hi) ^ (lo & 7)) * 8;
      bf16x8 af = *reinterpret_cast<const bf16x8*>(ar + g);
      bf16x8 bf_ = *reinterpret_cast<const bf16x8*>(br + g);
      acc = __builtin_amdgcn_mfma_f32_16x16x32_bf16(af, bf_, acc, 0, 0, 0);
    }
    if (kh == 1)
      *reinterpret_cast<f32x4*>(&red[ch][lane][0]) = acc;
    __syncthreads();
    if (kh == 0) {
      f32x4 o = *reinterpret_cast<const f32x4*>(&red[ch][lane][0]);
#pragma unroll
      for (int j = 0; j < 4; ++j) {
        float v = tanhf(acc[j] + o[j] + xw[j]);
        HALLB[((size_t)(n0 + hi * 4 + j) * T + t) * H + col] = f2b(v);
      }
      asm volatile("s_waitcnt vmcnt(0)" ::: "memory");
    }
    __syncthreads();
    if (t + 1 < T) {
      if (tid == 0)
        __hip_atomic_store(myflag, t + 1, __ATOMIC_RELAXED,
                           __HIP_MEMORY_SCOPE_AGENT);
      if (tid < 32) {
        int* fp = grpflags + tid * 16;
        int iter = 0;
        while (__hip_atomic_load(fp, __ATOMIC_RELAXED,
                                 __HIP_MEMORY_SCOPE_AGENT) < t + 1 &&
               iter < (1 << 17)) {
          ++iter;
          __builtin_amdgcn_s_sleep(1);
        }
      }
      __syncthreads();
    }
  }
}

// ---------- combine partials + target dot -> per-block nll sums ----------
__global__ __launch_bounds__(256) void k_loss(const float* __restrict__ psum,
                                              const unsigned short* __restrict__ HALLB,
                                              const unsigned short* __restrict__ WvT,
                                              const float* __restrict__ bv,
                                              const int* __restrict__ cap,
                                              float* __restrict__ blk) {
  int wave = threadIdx.x >> 6, lane = threadIdx.x & 63;
  int r = blockIdx.x * 4 + wave;
  float S = 0.f;
  for (int i = lane; i < NP; i += 64) S += psum[(size_t)r * NP + i];
#pragma unroll
  for (int off = 32; off >= 1; off >>= 1) S += __shfl_xor(S, off);
  float lse = 8.0f + logf(S);
  int n = r >> 5, t = r & 31;
  int tok = cap[n * 33 + t + 1];
  const unsigned short* hr = HALLB + (size_t)r * H + lane * 16;
  const unsigned short* wr_ = WvT + (size_t)tok * H + lane * 16;
  float d = 0.f;
#pragma unroll
  for (int i = 0; i < 16; ++i) d += b2f(hr[i]) * b2f(wr_[i]);
#pragma unroll
  for (int off = 32; off >= 1; off >>= 1) d += __shfl_xor(d, off);
  float nll = (tok != 0) ? (lse - (d + bv[tok])) : 0.f;
  __shared__ float red[4];
  if (lane == 0) red[wave] = nll;
  __syncthreads();
  if (threadIdx.x == 0) blk[blockIdx.x] = red[0] + red[1] + red[2] + red[3];
}

__global__ __launch_bounds__(256) void k_final(const float* __restrict__ blk,
                                               float* __restrict__ out) {
  __shared__ float red[256];
  float s = 0.f;
  for (int i = threadIdx.x; i < R / 4; i += 256) s += blk[i];
  red[threadIdx.x] = s;
  __syncthreads();
  for (int st = 128; st >= 1; st >>= 1) {
    if (threadIdx.x < st) red[threadIdx.x] += red[threadIdx.x + st];
    __syncthreads();
  }
  if (threadIdx.x == 0) out[0] = red[0] * (1.0f / 128.0f);
}

}  // namespace

extern "C" void kernel_launch(void* const* d_in, const int* in_sizes, int n_in,
                              void* d_out, int out_size, void* d_ws, size_t ws_size,
                              hipStream_t stream) {
  const float* feat = (const float*)d_in[0];
  const int*   cap  = (const int*)d_in[1];
  const float* Wp   = (const float*)d_in[2];
  const float* bp   = (const float*)d_in[3];
  const float* Wemb = (const float*)d_in[4];
  const float* Wx   = (const float*)d_in[5];
  const float* Wh   = (const float*)d_in[6];
  const float* b    = (const float*)d_in[7];
  const float* Wv   = (const float*)d_in[8];
  const float* bv   = (const float*)d_in[9];

  float* ws = (float*)d_ws;
  unsigned short* XB    = (unsigned short*)(ws + OFF_XB);
  unsigned short* featB = (unsigned short*)(ws + OFF_FEATB);
  unsigned short* h0B   = (unsigned short*)(ws + OFF_H0B);
  unsigned short* HALLB = (unsigned short*)(ws + OFF_HALLB);
  unsigned short* WpT   = (unsigned short*)(ws + OFF_WPT);
  unsigned short* WxT   = (unsigned short*)(ws + OFF_WXT);
  unsigned short* WhT   = (unsigned short*)(ws + OFF_WHT);
  unsigned short* WvT   = (unsigned short*)(ws + OFF_WVT);
  float* xW   = ws + OFF_XW;
  float* psum = ws + OFF_PSUM;
  float* blk  = ws + OFF_BLK;
  int*   bar  = (int*)(ws + OFF_BAR);

  hipMemsetAsync(bar, 0, 4224 * sizeof(int), stream);

  hipLaunchKernelGGL(k_cvt_t_all, dim3(4608), dim3(256), 0, stream,
                     Wv, Wh, Wp, Wx, WvT, WhT, WpT, WxT);
  hipLaunchKernelGGL(k_inputs, dim3(4224), dim3(256), 0, stream,
                     cap, Wemb, feat, XB, featB);

  // h0 = featB @ Wp^T + bp   (bf16 out)
  hipLaunchKernelGGL((gemm_bt<128, 128, 64, 64, 1>), dim3(H / 128, 1), dim3(256), 0, stream,
                     featB, D, WpT, D, (void*)h0B, H, bp);
  // xW = XB @ Wx^T + b   (f32 out)
  hipLaunchKernelGGL((gemm_bt<128, 128, 64, 64, 0>), dim3(H / 128, R / 128), dim3(256), 0, stream,
                     XB, D, WxT, D, (void*)xW, H, b);
  // full recurrence: 8 independent XCD-local RNNs, one dispatch
  hipLaunchKernelGGL(k_rnn_persist, dim3(256), dim3(256), 0, stream,
                     h0B, WhT, xW, HALLB, bar);
  // scores partials: 8-phase 256^2 counted-vmcnt GEMM, XCD-aware decode
  hipLaunchKernelGGL(k_scores8, dim3((V / 256) * (R / 256)), dim3(512), 0, stream,
                     HALLB, WvT, bv, psum);
  hipLaunchKernelGGL(k_loss, dim3(R / 4), dim3(256), 0, stream,
                     psum, HALLB, WvT, bv, cap, blk);
  hipLaunchKernelGGL(k_final, dim3(1), dim3(256), 0, stream, blk, (float*)d_out);
}